// Round 1
// baseline (169.312 us; speedup 1.0000x reference)
//
#include <hip/hip_runtime.h>

namespace {
constexpr int DEPTH   = 11;
constexpr int IN_W    = 768;
constexpr int LEAF_W  = 16;
constexpr int OUT_W   = 768;
constexpr int N_NODES = (1 << DEPTH) - 1;   // 2047
constexpr int BATCH   = 8192;
}

// One wave (64 lanes) per sample. Block = 256 threads = 4 samples.
// Routing dot products accumulate in fp64 so our decision boundary error
// (~3e-8) is far below the fp32 numpy reference's own rounding (~1e-7):
// a flipped routing decision sends the sample to a different leaf (O(1) error).
__global__ __launch_bounds__(256, 4) void fff_fused(
    const float* __restrict__ x,
    const float* __restrict__ nw,
    const float* __restrict__ nb,
    const float* __restrict__ w1,
    const float* __restrict__ b1,
    const float* __restrict__ w2,
    float* __restrict__ out)
{
    const int lane = threadIdx.x & 63;
    const int s    = (int)((blockIdx.x * blockDim.x + threadIdx.x) >> 6);

    // ---- load this sample's x slice: 12 contiguous floats per lane ----
    const float* xp = x + (size_t)s * IN_W + lane * 12;
    const float4 xv0 = *(const float4*)(xp + 0);
    const float4 xv1 = *(const float4*)(xp + 4);
    const float4 xv2 = *(const float4*)(xp + 8);
    const float xs[12] = {xv0.x, xv0.y, xv0.z, xv0.w,
                          xv1.x, xv1.y, xv1.z, xv1.w,
                          xv2.x, xv2.y, xv2.z, xv2.w};

    // ---- tree routing: 11 serial gather-dot levels, fp64 accumulation ----
    int node = 0;
    #pragma unroll 1
    for (int d = 0; d < DEPTH; ++d) {
        const float* wp = nw + (size_t)node * IN_W + lane * 12;
        const float4 a0 = *(const float4*)(wp + 0);
        const float4 a1 = *(const float4*)(wp + 4);
        const float4 a2 = *(const float4*)(wp + 8);
        const float wa[12] = {a0.x, a0.y, a0.z, a0.w,
                              a1.x, a1.y, a1.z, a1.w,
                              a2.x, a2.y, a2.z, a2.w};
        double acc = 0.0;
        #pragma unroll
        for (int j = 0; j < 12; ++j)
            acc = fma((double)wa[j], (double)xs[j], acc);
        // butterfly reduce over 64 lanes; all lanes end with bitwise-identical
        // sums (commutative pairwise adds) -> node stays wave-uniform.
        #pragma unroll
        for (int off = 32; off > 0; off >>= 1)
            acc += __shfl_xor(acc, off, 64);
        const double score = acc + (double)nb[node];
        node = 2 * node + 1 + (score >= 0.0 ? 1 : 0);
    }
    const int leaf = node - N_NODES;

    // ---- layer 1: h[l] = sum_i x[i] * w1[leaf][i][l]  (lane owns 12 rows) ----
    const float* w1p = w1 + (size_t)leaf * (IN_W * LEAF_W) + (size_t)lane * 12 * LEAF_W;
    float h[LEAF_W];
    #pragma unroll
    for (int l = 0; l < LEAF_W; ++l) h[l] = 0.f;
    #pragma unroll
    for (int r = 0; r < 12; ++r) {
        const float xi = xs[r];
        const float4 c0 = *(const float4*)(w1p + r * LEAF_W + 0);
        const float4 c1 = *(const float4*)(w1p + r * LEAF_W + 4);
        const float4 c2 = *(const float4*)(w1p + r * LEAF_W + 8);
        const float4 c3 = *(const float4*)(w1p + r * LEAF_W + 12);
        const float c[16] = {c0.x, c0.y, c0.z, c0.w, c1.x, c1.y, c1.z, c1.w,
                             c2.x, c2.y, c2.z, c2.w, c3.x, c3.y, c3.z, c3.w};
        #pragma unroll
        for (int l = 0; l < LEAF_W; ++l) h[l] = fmaf(xi, c[l], h[l]);
    }
    // reduce h across the 64 lanes (butterfly, identical on all lanes)
    #pragma unroll
    for (int l = 0; l < LEAF_W; ++l) {
        float v = h[l];
        #pragma unroll
        for (int off = 32; off > 0; off >>= 1) v += __shfl_xor(v, off, 64);
        h[l] = v;
    }
    // bias + relu (uniform broadcast loads)
    const float* b1p = b1 + (size_t)leaf * LEAF_W;
    #pragma unroll
    for (int l = 0; l < LEAF_W; ++l) h[l] = fmaxf(h[l] + b1p[l], 0.f);

    // ---- layer 2: out[o] = sum_l h[l] * w2[leaf][l][o]  (lane owns 12 cols) ----
    const float* w2p = w2 + (size_t)leaf * (LEAF_W * OUT_W) + lane * 12;
    float oacc[12];
    #pragma unroll
    for (int j = 0; j < 12; ++j) oacc[j] = 0.f;
    #pragma unroll
    for (int l = 0; l < LEAF_W; ++l) {
        const float hl = h[l];
        const float4 r0 = *(const float4*)(w2p + l * OUT_W + 0);
        const float4 r1 = *(const float4*)(w2p + l * OUT_W + 4);
        const float4 r2 = *(const float4*)(w2p + l * OUT_W + 8);
        const float rr[12] = {r0.x, r0.y, r0.z, r0.w,
                              r1.x, r1.y, r1.z, r1.w,
                              r2.x, r2.y, r2.z, r2.w};
        #pragma unroll
        for (int j = 0; j < 12; ++j) oacc[j] = fmaf(hl, rr[j], oacc[j]);
    }

    float* op = out + (size_t)s * OUT_W + lane * 12;
    *(float4*)(op + 0) = make_float4(oacc[0], oacc[1], oacc[2],  oacc[3]);
    *(float4*)(op + 4) = make_float4(oacc[4], oacc[5], oacc[6],  oacc[7]);
    *(float4*)(op + 8) = make_float4(oacc[8], oacc[9], oacc[10], oacc[11]);
}

extern "C" void kernel_launch(void* const* d_in, const int* in_sizes, int n_in,
                              void* d_out, int out_size, void* d_ws, size_t ws_size,
                              hipStream_t stream) {
    const float* x  = (const float*)d_in[0];
    const float* nw = (const float*)d_in[1];
    const float* nb = (const float*)d_in[2];
    const float* w1 = (const float*)d_in[3];
    const float* b1 = (const float*)d_in[4];
    const float* w2 = (const float*)d_in[5];
    float* o        = (float*)d_out;

    const int waves_per_block = 256 / 64;              // 4 samples per block
    const int grid = BATCH / waves_per_block;          // 2048 blocks
    fff_fused<<<dim3(grid), dim3(256), 0, stream>>>(x, nw, nb, w1, b1, w2, o);
}

// Round 2
// 150.919 us; speedup vs baseline: 1.1219x; 1.1219x over previous
//
#include <hip/hip_runtime.h>

namespace {
constexpr int DEPTH    = 11;
constexpr int IN_W     = 768;
constexpr int LEAF_W   = 16;
constexpr int OUT_W    = 768;
constexpr int N_NODES  = (1 << DEPTH) - 1;   // 2047
constexpr int N_LEAVES = (1 << DEPTH);       // 2048
constexpr int BATCH    = 8192;
}

// ---------------- Kernel A: tree routing (one wave per sample) ----------------
// fp64 accumulation keeps decision-boundary error (~3e-8) far below the fp32
// numpy reference's own rounding (~1e-7) -> routing decisions match.
__global__ __launch_bounds__(256) void fff_route(
    const float* __restrict__ x,
    const float* __restrict__ nw,
    const float* __restrict__ nb,
    int* __restrict__ leaf_of,   // [BATCH]
    int* __restrict__ rank_of,   // [BATCH]
    int* __restrict__ cnt)       // [N_LEAVES], pre-zeroed
{
    const int lane = threadIdx.x & 63;
    const int s    = (int)((blockIdx.x * blockDim.x + threadIdx.x) >> 6);

    const float* xp = x + (size_t)s * IN_W + lane * 12;
    const float4 xv0 = *(const float4*)(xp + 0);
    const float4 xv1 = *(const float4*)(xp + 4);
    const float4 xv2 = *(const float4*)(xp + 8);
    const float xs[12] = {xv0.x, xv0.y, xv0.z, xv0.w,
                          xv1.x, xv1.y, xv1.z, xv1.w,
                          xv2.x, xv2.y, xv2.z, xv2.w};

    int node = 0;
    #pragma unroll 1
    for (int d = 0; d < DEPTH; ++d) {
        const float* wp = nw + (size_t)node * IN_W + lane * 12;
        const float4 a0 = *(const float4*)(wp + 0);
        const float4 a1 = *(const float4*)(wp + 4);
        const float4 a2 = *(const float4*)(wp + 8);
        const float wa[12] = {a0.x, a0.y, a0.z, a0.w,
                              a1.x, a1.y, a1.z, a1.w,
                              a2.x, a2.y, a2.z, a2.w};
        double acc = 0.0;
        #pragma unroll
        for (int j = 0; j < 12; ++j)
            acc = fma((double)wa[j], (double)xs[j], acc);
        #pragma unroll
        for (int off = 32; off > 0; off >>= 1)
            acc += __shfl_xor(acc, off, 64);
        const double score = acc + (double)nb[node];
        node = 2 * node + 1 + (score >= 0.0 ? 1 : 0);
    }
    const int leaf = node - N_NODES;

    if (lane == 0) {
        leaf_of[s] = leaf;
        rank_of[s] = atomicAdd(&cnt[leaf], 1);
    }
}

// ---------------- Kernel B: exclusive scan of 2048 counts (one wave) ----------------
__global__ void fff_scan(const int* __restrict__ cnt, int* __restrict__ off) {
    const int lane = threadIdx.x & 63;      // launched with 64 threads
    const int base = lane * (N_LEAVES / 64);  // 32 leaves per lane
    int local[N_LEAVES / 64];
    int sum = 0;
    #pragma unroll
    for (int i = 0; i < N_LEAVES / 64; ++i) { local[i] = cnt[base + i]; sum += local[i]; }
    int v = sum;
    #pragma unroll
    for (int d = 1; d < 64; d <<= 1) {
        int u = __shfl_up(v, d, 64);
        if (lane >= d) v += u;
    }
    int run = v - sum;   // exclusive prefix of this lane's chunk
    #pragma unroll
    for (int i = 0; i < N_LEAVES / 64; ++i) { off[base + i] = run; run += local[i]; }
}

// ---------------- Kernel C: scatter samples into leaf-sorted order ----------------
__global__ __launch_bounds__(256) void fff_scatter(
    const int* __restrict__ leaf_of, const int* __restrict__ rank_of,
    const int* __restrict__ off, int* __restrict__ sorted)
{
    const int s = blockIdx.x * blockDim.x + threadIdx.x;
    if (s < BATCH) sorted[off[leaf_of[s]] + rank_of[s]] = s;
}

// ---------------- Kernel D: leaf MLP, one block (4 waves) per leaf ----------------
// All waves of a block share one leaf's weights -> each leaf's 96 KB is fetched
// from HBM once and served to sibling waves from L1/L2.
__global__ __launch_bounds__(256) void fff_leaf_mlp(
    const float* __restrict__ x,
    const float* __restrict__ w1,
    const float* __restrict__ b1,
    const float* __restrict__ w2,
    const int* __restrict__ cnt,
    const int* __restrict__ off,
    const int* __restrict__ sorted,
    float* __restrict__ out)
{
    const int leaf = blockIdx.x;
    const int n    = cnt[leaf];
    if (n == 0) return;
    const int wid  = threadIdx.x >> 6;
    const int lane = threadIdx.x & 63;
    const int o0   = off[leaf];

    const float* w1p = w1 + (size_t)leaf * (IN_W * LEAF_W) + (size_t)lane * 12 * LEAF_W;
    const float* b1p = b1 + (size_t)leaf * LEAF_W;
    const float* w2p = w2 + (size_t)leaf * (LEAF_W * OUT_W) + lane * 12;

    for (int i = wid; i < n; i += 4) {
        const int s = sorted[o0 + i];

        const float* xp = x + (size_t)s * IN_W + lane * 12;
        const float4 xv0 = *(const float4*)(xp + 0);
        const float4 xv1 = *(const float4*)(xp + 4);
        const float4 xv2 = *(const float4*)(xp + 8);
        const float xs[12] = {xv0.x, xv0.y, xv0.z, xv0.w,
                              xv1.x, xv1.y, xv1.z, xv1.w,
                              xv2.x, xv2.y, xv2.z, xv2.w};

        // layer 1: lane owns 12 w1 rows (768 B contiguous)
        float h[LEAF_W];
        #pragma unroll
        for (int l = 0; l < LEAF_W; ++l) h[l] = 0.f;
        #pragma unroll
        for (int r = 0; r < 12; ++r) {
            const float xi = xs[r];
            const float4 c0 = *(const float4*)(w1p + r * LEAF_W + 0);
            const float4 c1 = *(const float4*)(w1p + r * LEAF_W + 4);
            const float4 c2 = *(const float4*)(w1p + r * LEAF_W + 8);
            const float4 c3 = *(const float4*)(w1p + r * LEAF_W + 12);
            const float c[16] = {c0.x, c0.y, c0.z, c0.w, c1.x, c1.y, c1.z, c1.w,
                                 c2.x, c2.y, c2.z, c2.w, c3.x, c3.y, c3.z, c3.w};
            #pragma unroll
            for (int l = 0; l < LEAF_W; ++l) h[l] = fmaf(xi, c[l], h[l]);
        }
        #pragma unroll
        for (int l = 0; l < LEAF_W; ++l) {
            float v = h[l];
            #pragma unroll
            for (int o2 = 32; o2 > 0; o2 >>= 1) v += __shfl_xor(v, o2, 64);
            h[l] = fmaxf(v + b1p[l], 0.f);
        }

        // layer 2: lane owns 12 output cols
        float oacc[12];
        #pragma unroll
        for (int j = 0; j < 12; ++j) oacc[j] = 0.f;
        #pragma unroll
        for (int l = 0; l < LEAF_W; ++l) {
            const float hl = h[l];
            const float4 r0 = *(const float4*)(w2p + l * OUT_W + 0);
            const float4 r1 = *(const float4*)(w2p + l * OUT_W + 4);
            const float4 r2 = *(const float4*)(w2p + l * OUT_W + 8);
            const float rr[12] = {r0.x, r0.y, r0.z, r0.w,
                                  r1.x, r1.y, r1.z, r1.w,
                                  r2.x, r2.y, r2.z, r2.w};
            #pragma unroll
            for (int j = 0; j < 12; ++j) oacc[j] = fmaf(hl, rr[j], oacc[j]);
        }

        float* op = out + (size_t)s * OUT_W + lane * 12;
        *(float4*)(op + 0) = make_float4(oacc[0], oacc[1], oacc[2],  oacc[3]);
        *(float4*)(op + 4) = make_float4(oacc[4], oacc[5], oacc[6],  oacc[7]);
        *(float4*)(op + 8) = make_float4(oacc[8], oacc[9], oacc[10], oacc[11]);
    }
}

extern "C" void kernel_launch(void* const* d_in, const int* in_sizes, int n_in,
                              void* d_out, int out_size, void* d_ws, size_t ws_size,
                              hipStream_t stream) {
    const float* x  = (const float*)d_in[0];
    const float* nw = (const float*)d_in[1];
    const float* nb = (const float*)d_in[2];
    const float* w1 = (const float*)d_in[3];
    const float* b1 = (const float*)d_in[4];
    const float* w2 = (const float*)d_in[5];
    float* o        = (float*)d_out;

    // workspace layout (ints): cnt[2048] | off[2048] | leaf[8192] | rank[8192] | sorted[8192]
    int* cnt    = (int*)d_ws;
    int* off    = cnt + N_LEAVES;
    int* leaf   = off + N_LEAVES;
    int* rank   = leaf + BATCH;
    int* sorted = rank + BATCH;

    hipMemsetAsync(cnt, 0, N_LEAVES * sizeof(int), stream);

    fff_route  <<<dim3(BATCH / 4), dim3(256), 0, stream>>>(x, nw, nb, leaf, rank, cnt);
    fff_scan   <<<dim3(1),         dim3(64),  0, stream>>>(cnt, off);
    fff_scatter<<<dim3(BATCH/256), dim3(256), 0, stream>>>(leaf, rank, off, sorted);
    fff_leaf_mlp<<<dim3(N_LEAVES), dim3(256), 0, stream>>>(x, w1, b1, w2, cnt, off, sorted, o);
}

// Round 3
// 133.187 us; speedup vs baseline: 1.2712x; 1.1331x over previous
//
#include <hip/hip_runtime.h>

namespace {
constexpr int DEPTH    = 11;
constexpr int IN_W     = 768;
constexpr int LEAF_W   = 16;
constexpr int OUT_W    = 768;
constexpr int N_NODES  = (1 << DEPTH) - 1;   // 2047
constexpr int N_LEAVES = (1 << DEPTH);       // 2048
constexpr int BATCH    = 8192;
}

// ---------------- Kernel A: tree routing (one wave per sample) ----------------
// fp64 accumulation keeps decision-boundary error (~3e-8) far below the fp32
// numpy reference's own rounding (~1e-7) -> routing decisions match.
__global__ __launch_bounds__(256) void fff_route(
    const float* __restrict__ x,
    const float* __restrict__ nw,
    const float* __restrict__ nb,
    int* __restrict__ leaf_of,   // [BATCH]
    int* __restrict__ rank_of,   // [BATCH]
    int* __restrict__ cnt)       // [N_LEAVES], pre-zeroed
{
    const int lane = threadIdx.x & 63;
    const int s    = (int)((blockIdx.x * blockDim.x + threadIdx.x) >> 6);

    const float* xp = x + (size_t)s * IN_W + lane * 12;
    const float4 xv0 = *(const float4*)(xp + 0);
    const float4 xv1 = *(const float4*)(xp + 4);
    const float4 xv2 = *(const float4*)(xp + 8);
    const float xs[12] = {xv0.x, xv0.y, xv0.z, xv0.w,
                          xv1.x, xv1.y, xv1.z, xv1.w,
                          xv2.x, xv2.y, xv2.z, xv2.w};

    int node = 0;
    #pragma unroll 1
    for (int d = 0; d < DEPTH; ++d) {
        const float* wp = nw + (size_t)node * IN_W + lane * 12;
        const float4 a0 = *(const float4*)(wp + 0);
        const float4 a1 = *(const float4*)(wp + 4);
        const float4 a2 = *(const float4*)(wp + 8);
        const float wa[12] = {a0.x, a0.y, a0.z, a0.w,
                              a1.x, a1.y, a1.z, a1.w,
                              a2.x, a2.y, a2.z, a2.w};
        double acc = 0.0;
        #pragma unroll
        for (int j = 0; j < 12; ++j)
            acc = fma((double)wa[j], (double)xs[j], acc);
        #pragma unroll
        for (int off = 32; off > 0; off >>= 1)
            acc += __shfl_xor(acc, off, 64);
        const double score = acc + (double)nb[node];
        node = 2 * node + 1 + (score >= 0.0 ? 1 : 0);
    }
    const int leaf = node - N_NODES;

    if (lane == 0) {
        leaf_of[s] = leaf;
        rank_of[s] = atomicAdd(&cnt[leaf], 1);
    }
}

// ---------------- Kernel B: exclusive scan of 2048 counts (one wave) ----------------
__global__ void fff_scan(const int* __restrict__ cnt, int* __restrict__ off) {
    const int lane = threadIdx.x & 63;        // launched with 64 threads
    const int base = lane * (N_LEAVES / 64);  // 32 leaves per lane
    int local[N_LEAVES / 64];
    int sum = 0;
    #pragma unroll
    for (int i = 0; i < N_LEAVES / 64; ++i) { local[i] = cnt[base + i]; sum += local[i]; }
    int v = sum;
    #pragma unroll
    for (int d = 1; d < 64; d <<= 1) {
        int u = __shfl_up(v, d, 64);
        if (lane >= d) v += u;
    }
    int run = v - sum;   // exclusive prefix of this lane's chunk
    #pragma unroll
    for (int i = 0; i < N_LEAVES / 64; ++i) { off[base + i] = run; run += local[i]; }
}

// ---------------- Kernel C: scatter samples into leaf-sorted order ----------------
__global__ __launch_bounds__(256) void fff_scatter(
    const int* __restrict__ leaf_of, const int* __restrict__ rank_of,
    const int* __restrict__ off,
    int* __restrict__ sorted, int* __restrict__ leaf_sorted)
{
    const int s = blockIdx.x * blockDim.x + threadIdx.x;
    if (s < BATCH) {
        const int lf = leaf_of[s];
        const int i  = off[lf] + rank_of[s];
        sorted[i]      = s;
        leaf_sorted[i] = lf;
    }
}

// ---------------- Kernel D: leaf MLP, one wave per sorted position ----------------
// Perfect load balance (8192 waves, 1 sample each). Same-leaf samples are
// adjacent in sorted order -> sibling waves in a block share one leaf's 96 KB
// of weights (L1 hits); larger leaves span consecutive blocks (L2/LLC hits).
__global__ __launch_bounds__(256, 4) void fff_leaf_mlp2(
    const float* __restrict__ x,
    const float* __restrict__ w1,
    const float* __restrict__ b1,
    const float* __restrict__ w2,
    const int* __restrict__ sorted,
    const int* __restrict__ leaf_sorted,
    float* __restrict__ out)
{
    const int lane = threadIdx.x & 63;
    const int i    = (int)((blockIdx.x * blockDim.x + threadIdx.x) >> 6);
    const int s    = sorted[i];
    const int leaf = leaf_sorted[i];

    const float* xp = x + (size_t)s * IN_W + lane * 12;
    const float4 xv0 = *(const float4*)(xp + 0);
    const float4 xv1 = *(const float4*)(xp + 4);
    const float4 xv2 = *(const float4*)(xp + 8);
    const float xs[12] = {xv0.x, xv0.y, xv0.z, xv0.w,
                          xv1.x, xv1.y, xv1.z, xv1.w,
                          xv2.x, xv2.y, xv2.z, xv2.w};

    // layer 1: lane owns 12 w1 rows (768 B contiguous)
    const float* w1p = w1 + (size_t)leaf * (IN_W * LEAF_W) + (size_t)lane * 12 * LEAF_W;
    float h[LEAF_W];
    #pragma unroll
    for (int l = 0; l < LEAF_W; ++l) h[l] = 0.f;
    #pragma unroll
    for (int r = 0; r < 12; ++r) {
        const float xi = xs[r];
        const float4 c0 = *(const float4*)(w1p + r * LEAF_W + 0);
        const float4 c1 = *(const float4*)(w1p + r * LEAF_W + 4);
        const float4 c2 = *(const float4*)(w1p + r * LEAF_W + 8);
        const float4 c3 = *(const float4*)(w1p + r * LEAF_W + 12);
        const float c[16] = {c0.x, c0.y, c0.z, c0.w, c1.x, c1.y, c1.z, c1.w,
                             c2.x, c2.y, c2.z, c2.w, c3.x, c3.y, c3.z, c3.w};
        #pragma unroll
        for (int l = 0; l < LEAF_W; ++l) h[l] = fmaf(xi, c[l], h[l]);
    }
    #pragma unroll
    for (int l = 0; l < LEAF_W; ++l) {
        float v = h[l];
        #pragma unroll
        for (int o2 = 32; o2 > 0; o2 >>= 1) v += __shfl_xor(v, o2, 64);
        h[l] = v;
    }
    const float* b1p = b1 + (size_t)leaf * LEAF_W;
    #pragma unroll
    for (int l = 0; l < LEAF_W; ++l) h[l] = fmaxf(h[l] + b1p[l], 0.f);

    // layer 2: lane owns 12 output cols
    const float* w2p = w2 + (size_t)leaf * (LEAF_W * OUT_W) + lane * 12;
    float oacc[12];
    #pragma unroll
    for (int j = 0; j < 12; ++j) oacc[j] = 0.f;
    #pragma unroll
    for (int l = 0; l < LEAF_W; ++l) {
        const float hl = h[l];
        const float4 r0 = *(const float4*)(w2p + l * OUT_W + 0);
        const float4 r1 = *(const float4*)(w2p + l * OUT_W + 4);
        const float4 r2 = *(const float4*)(w2p + l * OUT_W + 8);
        const float rr[12] = {r0.x, r0.y, r0.z, r0.w,
                              r1.x, r1.y, r1.z, r1.w,
                              r2.x, r2.y, r2.z, r2.w};
        #pragma unroll
        for (int j = 0; j < 12; ++j) oacc[j] = fmaf(hl, rr[j], oacc[j]);
    }

    float* op = out + (size_t)s * OUT_W + lane * 12;
    *(float4*)(op + 0) = make_float4(oacc[0], oacc[1], oacc[2],  oacc[3]);
    *(float4*)(op + 4) = make_float4(oacc[4], oacc[5], oacc[6],  oacc[7]);
    *(float4*)(op + 8) = make_float4(oacc[8], oacc[9], oacc[10], oacc[11]);
}

extern "C" void kernel_launch(void* const* d_in, const int* in_sizes, int n_in,
                              void* d_out, int out_size, void* d_ws, size_t ws_size,
                              hipStream_t stream) {
    const float* x  = (const float*)d_in[0];
    const float* nw = (const float*)d_in[1];
    const float* nb = (const float*)d_in[2];
    const float* w1 = (const float*)d_in[3];
    const float* b1 = (const float*)d_in[4];
    const float* w2 = (const float*)d_in[5];
    float* o        = (float*)d_out;

    // workspace (ints): cnt[2048] | off[2048] | leaf[8192] | rank[8192] | sorted[8192] | leafs[8192]
    int* cnt    = (int*)d_ws;
    int* off    = cnt + N_LEAVES;
    int* leaf   = off + N_LEAVES;
    int* rank   = leaf + BATCH;
    int* sorted = rank + BATCH;
    int* leafs  = sorted + BATCH;

    hipMemsetAsync(cnt, 0, N_LEAVES * sizeof(int), stream);

    fff_route   <<<dim3(BATCH / 4), dim3(256), 0, stream>>>(x, nw, nb, leaf, rank, cnt);
    fff_scan    <<<dim3(1),         dim3(64),  0, stream>>>(cnt, off);
    fff_scatter <<<dim3(BATCH/256), dim3(256), 0, stream>>>(leaf, rank, off, sorted, leafs);
    fff_leaf_mlp2<<<dim3(BATCH / 4), dim3(256), 0, stream>>>(x, w1, b1, w2, sorted, leafs, o);
}